// Round 3
// baseline (24.298 us; speedup 1.0000x reference)
//
#include <hip/hip_runtime.h>

#define SEQ 4096
#define DIM 1024
#define NB  8
#define NP  8
#define M   64          // NB*NP rows
#define KSPLIT 8        // K-split factor
#define KBLK  (DIM / KSPLIT)   // 128
#define NCT   16        // 64-wide column tiles
#define LDSP  68        // padded LDS row stride (floats)

// ---------------------------------------------------------------------------
// Kernel 1: grid = 64 blocks (b,p) x 256 thr. Wave-shfl mask scan -> first 8
// one-positions, then bucket-p mean (contiguous row range). Block 0 also
// zeroes the k2 reduction counters.
// ---------------------------------------------------------------------------
__global__ __launch_bounds__(256) void k_scan_mean(
    const float* __restrict__ latent,   // [NB][SEQ][DIM]
    const int*   __restrict__ mask,     // [NB][SEQ]
    float*       __restrict__ mean,     // [NB][NP][DIM] (ws)
    int*         __restrict__ counters) // [NCT] (ws)
{
    const int b    = blockIdx.x >> 3;
    const int p    = blockIdx.x & 7;
    const int tid  = threadIdx.x;
    const int lane = tid & 63;
    const int wid  = tid >> 6;

    if (blockIdx.x == 0 && tid < NCT) counters[tid] = 0;

    __shared__ int s_pos[8];
    __shared__ int s_wsum[4];
    if (tid < 8) s_pos[tid] = SEQ;      // sentinel

    // 16 mask ints per thread
    int4 mv[4];
    const int4* m4 = (const int4*)(mask + (size_t)b * SEQ + tid * 16);
    int cnt = 0;
    #pragma unroll
    for (int i = 0; i < 4; ++i) {
        mv[i] = m4[i];
        cnt += mv[i].x + mv[i].y + mv[i].z + mv[i].w;
    }

    // wave-level inclusive scan (no syncs)
    int v = cnt;
    #pragma unroll
    for (int off = 1; off < 64; off <<= 1) {
        int o = __shfl_up(v, off, 64);
        if (lane >= off) v += o;
    }
    if (lane == 63) s_wsum[wid] = v;
    __syncthreads();                    // covers s_pos init + s_wsum

    int pre = 0;
    #pragma unroll
    for (int w = 0; w < 4; ++w) if (w < wid) pre += s_wsum[w];
    const int excl = pre + v - cnt;     // ones strictly before my chunk

    if (excl < 8) {                     // record first-8 one positions
        int rank = excl;
        const int* me = (const int*)mv;
        #pragma unroll
        for (int i = 0; i < 16; ++i) {
            if (me[i]) {
                if (rank < 8) s_pos[rank] = tid * 16 + i;
                ++rank;
            }
        }
    }
    __syncthreads();

    // bucket p = rows (pos[p-1], min(pos[p], SEQ-1)]
    const int start = (p == 0) ? 0 : s_pos[p - 1] + 1;
    const int endi  = min(s_pos[p], SEQ - 1);
    const float4* lb = (const float4*)(latent + (size_t)b * SEQ * DIM);
    float4 acc = make_float4(0.f, 0.f, 0.f, 0.f);
    for (int r = start; r <= endi; ++r) {
        float4 x = lb[(size_t)r * (DIM / 4) + tid];
        acc.x += x.x; acc.y += x.y; acc.z += x.z; acc.w += x.w;
    }
    const int count = endi - start + 1;
    const float inv = (count > 0) ? 1.0f / (float)count : 0.0f;
    acc.x *= inv; acc.y *= inv; acc.z *= inv; acc.w *= inv;
    ((float4*)(mean + (size_t)(b * NP + p) * DIM))[tid] = acc;
}

// ---------------------------------------------------------------------------
// Kernel 2: grid (NCT, KSPLIT) x 512 thr. Partial GEMM 64x64xKBLK, then
// last-arriving block per column tile reduces the 8 partials (fixed order),
// adds bias, writes out. Device-scope fences per G16.
// ---------------------------------------------------------------------------
__global__ __launch_bounds__(512) void k_gemm_fused(
    const float* __restrict__ mean,     // [M][DIM]
    const float* __restrict__ Wm,       // [DIM][DIM] row-major
    const float* __restrict__ bias,     // [DIM]
    float*       __restrict__ partial,  // [KSPLIT][NCT][64*64] (ws)
    int*         __restrict__ counters, // [NCT] (ws, zeroed by k1)
    float*       __restrict__ out)      // [M][DIM]
{
    __shared__ float As[64][LDSP];      // As[r][kk]   (plain; reads broadcast)
    __shared__ float Bs[64][LDSP];      // Bs[c][slot] (XOR-swizzled f4 slots)
    __shared__ int   s_old;
    const int ct    = blockIdx.x;
    const int ks    = blockIdx.y;
    const int i0    = ct * 64;
    const int kbase = ks * KBLK;
    const int tid   = threadIdx.x;
    const int tx    = tid & 15;         // col group (4 cols)
    const int ty    = tid >> 4;         // row group (2 rows), 0..31
    float acc[2][4] = {};

    for (int k0 = kbase; k0 < kbase + KBLK; k0 += 64) {
        #pragma unroll
        for (int l = 0; l < 2; ++l) {
            const int f4 = tid + l * 512;        // 0..1023
            const int r  = f4 >> 4;              // 0..63
            const int c4 = f4 & 15;              // f4-slot 0..15
            *(float4*)&As[r][c4 * 4] =
                *(const float4*)&mean[(size_t)r * DIM + k0 + c4 * 4];
            const int slot = c4 ^ ((r >> 2) & 15);   // bank-spread swizzle
            *(float4*)&Bs[r][slot * 4] =
                *(const float4*)&Wm[(size_t)(i0 + r) * DIM + k0 + c4 * 4];
        }
        __syncthreads();
        #pragma unroll
        for (int kk4 = 0; kk4 < 16; ++kk4) {
            float4 a0 = *(const float4*)&As[ty * 2 + 0][kk4 * 4];
            float4 a1 = *(const float4*)&As[ty * 2 + 1][kk4 * 4];
            const int rslot = (kk4 ^ tx) * 4;        // matches write swizzle
            float4 w[4];
            #pragma unroll
            for (int i = 0; i < 4; ++i)
                w[i] = *(const float4*)&Bs[tx * 4 + i][rslot];
            #pragma unroll
            for (int i = 0; i < 4; ++i) {
                acc[0][i] += a0.x * w[i].x + a0.y * w[i].y + a0.z * w[i].z + a0.w * w[i].w;
                acc[1][i] += a1.x * w[i].x + a1.y * w[i].y + a1.z * w[i].z + a1.w * w[i].w;
            }
        }
        __syncthreads();
    }

    // write 64x64 partial tile (contiguous)
    float* pt = partial + (size_t)(ks * NCT + ct) * 4096;
    #pragma unroll
    for (int j = 0; j < 2; ++j) {
        const int r = ty * 2 + j;
        *(float4*)&pt[r * 64 + tx * 4] =
            make_float4(acc[j][0], acc[j][1], acc[j][2], acc[j][3]);
    }

    __syncthreads();                    // drains vmcnt(0): stores in L2
    if (tid == 0) {
        __threadfence();                // L2 -> device scope (release)
        s_old = atomicAdd(&counters[ct], 1);
    }
    __syncthreads();
    if (s_old == KSPLIT - 1) {          // last arriver reduces (fixed order)
        __threadfence();                // acquire: invalidate stale L1/L2
        #pragma unroll
        for (int l = 0; l < 2; ++l) {
            const int f4 = tid + l * 512;
            const int r  = f4 >> 4;
            const int c4 = f4 & 15;
            float4 s = *(const float4*)&bias[i0 + c4 * 4];
            #pragma unroll
            for (int kr = 0; kr < KSPLIT; ++kr) {
                const float4 x = *(const float4*)
                    &partial[(size_t)(kr * NCT + ct) * 4096 + r * 64 + c4 * 4];
                s.x += x.x; s.y += x.y; s.z += x.z; s.w += x.w;
            }
            *(float4*)&out[(size_t)r * DIM + i0 + c4 * 4] = s;
        }
    }
}

extern "C" void kernel_launch(void* const* d_in, const int* in_sizes, int n_in,
                              void* d_out, int out_size, void* d_ws, size_t ws_size,
                              hipStream_t stream) {
    const float* latent = (const float*)d_in[0];   // (8,4096,1024) f32
    const int*   mask   = (const int*)d_in[1];     // (8,4096,1) int32
    const float* Wm     = (const float*)d_in[2];   // (1024,1024) f32
    const float* bias   = (const float*)d_in[3];   // (1024,) f32
    float* out     = (float*)d_out;                // (8,8,1024) f32
    float* mean    = (float*)d_ws;                 // 256 KB
    float* partial = mean + M * DIM;               // 2 MB
    int*   counters = (int*)(partial + KSPLIT * NCT * 4096);

    k_scan_mean<<<NB * NP, 256, 0, stream>>>(latent, mask, mean, counters);
    k_gemm_fused<<<dim3(NCT, KSPLIT), 512, 0, stream>>>(mean, Wm, bias,
                                                        partial, counters, out);
}